// Round 8
// baseline (758.013 us; speedup 1.0000x reference)
//
#include <hip/hip_runtime.h>

// Problem constants
#define T_ 4
#define B_ 16
#define C_ 512
#define N_ 1024
#define H_ 8
#define D_ 64
#define SPK_ELEMS (33554432ull)   // T*B*C*N

typedef _Float16 half8v __attribute__((ext_vector_type(8)));
typedef _Float16 half4v __attribute__((ext_vector_type(4)));
typedef float f32x4 __attribute__((ext_vector_type(4)));

// ---------------- workspace layout (bytes) ----------------
// sq:  [0, 33554432)            uint8 q spikes  [t,b,n,c]  (TRANSPOSED)
// sk:  [33554432, 67108864)     uint8 k spikes  [t,b,c,n]
// sv:  [67108864, 100663296)    uint8 v spikes  [t,b,c,n]
// kv:  [100663296, 109051904)   fp32  [t,b,h,d,e]
// wb:  [109051904, 113246208)   f16   [p=4][digit=2][512][512], W pre-scaled by 2^12
// xs:  [113246208, 247463936)   f16   [digit=2][t][b][n][c],    x pre-scaled by 2^11
// sa:  aliases xs digit-0 region (xs dead before attn writes it); f16 {0,1}
#define KV_OFF_N  100663296ull
#define WB_OFF_N  109051904ull
#define XS_OFF_N  113246208ull

#define QKV_INV_SCALE (1.0f / 8388608.0f)   // 2^-23  (Sx=2^11 * Sw=2^12)
#define PROJ_INV_SCALE (1.0f / 4096.0f)     // 2^-12  (Sw only; spikes unscaled)

#define GLD16(gp, loff) \
  __builtin_amdgcn_global_load_lds( \
      (const __attribute__((address_space(1))) void*)(gp), \
      (__attribute__((address_space(3))) void*)(lds + (loff)), 16, 0, 0)

// ---------------------------------------------------------------------------
// W [4 mats][512][512] fp32 -> wb [p][2][512][512] f16 digits of W*2^12.
// ---------------------------------------------------------------------------
__global__ __launch_bounds__(256) void convert_w(
    const float* __restrict__ w0, const float* __restrict__ w1,
    const float* __restrict__ w2, const float* __restrict__ w3,
    _Float16* __restrict__ wb)
{
  int idx = blockIdx.x * 256 + threadIdx.x;      // 0..1048575
  int p = idx >> 18, rem = idx & 262143;
  const float* src = (p == 0) ? w0 : (p == 1) ? w1 : (p == 2) ? w2 : w3;
  float v = src[rem] * 4096.0f;                  // exact pow2 scale
  _Float16 h1 = (_Float16)v;
  float r1 = v - (float)h1;
  _Float16 h2 = (_Float16)r1;
  size_t base = ((size_t)(p * 2)) << 18;
  wb[base + rem] = h1;
  wb[base + 262144 + rem] = h2;
}

// ---------------------------------------------------------------------------
// x [t,b,c,n] fp32 -> xs [digit=2][t,b,n,c] f16 digits of x*2^11 (transposed)
// ---------------------------------------------------------------------------
__global__ __launch_bounds__(256) void convert_x(
    const float* __restrict__ x, _Float16* __restrict__ xs)
{
  __shared__ float tile[32][33];
  const int tb = blockIdx.z;
  const int c0 = blockIdx.y * 32, n0 = blockIdx.x * 32;
  const int tx = threadIdx.x, ty = threadIdx.y;
  const float* src = x + ((size_t)tb * C_ + c0) * N_ + n0;
#pragma unroll
  for (int k = 0; k < 4; ++k)
    tile[ty + 8 * k][tx] = src[(size_t)(ty + 8 * k) * N_ + tx];
  __syncthreads();
#pragma unroll
  for (int k = 0; k < 4; ++k) {
    int r = ty + 8 * k;                       // n-offset within tile
    float v = tile[tx][r] * 2048.0f;          // exact pow2 scale
    _Float16 h1 = (_Float16)v;
    float r1 = v - (float)h1;
    _Float16 h2 = (_Float16)r1;
    size_t o = ((size_t)tb * N_ + n0 + r) * C_ + c0 + tx;
    xs[o] = h1;
    xs[o + 33554432ull] = h2;
  }
}

// ---------------------------------------------------------------------------
// Fused q/k/v GEMM (3-product f16 2x2-digit MFMA, fp32 acc) + LIF.
// Block tile 128o x 32n x 4t.  grid (12, 32, 16) + XCD-group swizzle (R5).
//
// R7: 512-thread blocks (8 waves = 4 o-quarters x 2 n-halves, 32o x 16n per
// wave).  Same LDS (W 2x16KB + X 3x16KB = 80KB), same 3-ring staging, same
// counted-vmcnt discipline (now vmcnt(6)/(4): 2 W + 2 X loads per thread).
// Waves/CU 8 -> 16 (4/SIMD): latency hiding across the barrier phases.
// ---------------------------------------------------------------------------
__global__ __launch_bounds__(512) void qkv_mfma(
    const _Float16* __restrict__ wb, const _Float16* __restrict__ xs,
    const float* __restrict__ bq, const float* __restrict__ bk,
    const float* __restrict__ bv, unsigned char* __restrict__ spikes_base)
{
  // LDS: W dbuf 2x16KB at [0,32768); X tribuf 3x16KB at [32768,81920)
  __shared__ __align__(16) char lds[81920];
  const int tid = threadIdx.x;
  const int lane = tid & 63, wave = tid >> 6;   // 0..7
  const int ln15 = lane & 15, lq = lane >> 4;
  const int wr = wave & 3, wn = wave >> 2;      // o-quarter, n-half

  // XCD-group swizzle (bijective: 6144 = 8 xcd x 64 chunks x 12 members)
  const int l = blockIdx.x + 12 * blockIdx.y + 384 * blockIdx.z;
  const int xcd = l & 7, slot = l >> 3;
  const int g = (slot / 12) * 8 + xcd;      // 0..511 -> (ntb, b)
  const int m = slot % 12;                  // 0..11  -> (ot | p)
  const int ot = m & 3, p = m >> 2;
  const int ntb = g & 31, b = g >> 5;
  const int o0 = ot * 128, n0 = ntb * 32;

#define WB_(k) (((k) & 1) * 16384)
#define XB_(k) (32768 + ((k) % 3) * 16384)

  // W staging sources: 2 x 16B per thread per k-step (16KB/step, 512 thr)
  const _Float16* gw[2];
#pragma unroll
  for (int i = 0; i < 2; ++i) {
    int u = i * 512 + tid;        // 0..1023: [dig s][row 128][chunk 4]
    int s = u >> 9, rem = u & 511;
    int row = rem >> 2, pc = rem & 3;
    int lc = pc ^ ((row >> 1) & 3);
    gw[i] = wb + (((size_t)(p * 2 + s)) << 18) + (size_t)(o0 + row) * C_ + lc * 8;
  }
  // X staging sources: 2 x 16B per thread per k-step (16KB/step)
  const _Float16* gx[2];
#pragma unroll
  for (int i = 0; i < 2; ++i) {
    int v = i * 512 + tid;        // 0..1023: [dig s][t 4][row 32][chunk 4]
    int s = v >> 9, rem = v & 511;
    int t = rem >> 7, rem2 = rem & 127;
    int row = rem2 >> 2, pc = rem2 & 3;
    int lc = pc ^ ((row >> 1) & 3);
    gx[i] = xs + ((size_t)s * 33554432ull) +
            ((size_t)((t * B_ + b) * N_ + n0 + row)) * C_ + lc * 8;
  }
  // LDS staging dest (wave-uniform base; lane*16 added by HW)
  const int sb = (tid & 448) * 16;   // wave * 1024

  f32x4 acc[T_][2];   // [t][mt]; wave's 32o x 16n slice
#pragma unroll
  for (int t = 0; t < T_; ++t)
#pragma unroll
    for (int mt = 0; mt < 2; ++mt)
      acc[t][mt] = (f32x4){0.f, 0.f, 0.f, 0.f};

  int offA[2][2], offB[2];
#pragma unroll
  for (int s = 0; s < 2; ++s) {
#pragma unroll
    for (int mt = 0; mt < 2; ++mt) {
      int r = wr * 32 + mt * 16 + ln15;
      offA[s][mt] = s * 8192 + r * 64 + ((lq ^ ((r >> 1) & 3)) << 4);
    }
    {
      int n = wn * 16 + ln15;
      offB[s] = s * 8192 + n * 64 + ((lq ^ ((n >> 1) & 3)) << 4);
    }
  }

  auto compute = [&](int wbase, int xbase) {
    half8v wa[2][2];
#pragma unroll
    for (int s = 0; s < 2; ++s)
#pragma unroll
      for (int mt = 0; mt < 2; ++mt)
        wa[s][mt] = *(const half8v*)&lds[wbase + offA[s][mt]];

    __builtin_amdgcn_s_setprio(1);
#pragma unroll
    for (int t = 0; t < T_; ++t) {
      half8v xb[2];
#pragma unroll
      for (int s = 0; s < 2; ++s)
        xb[s] = *(const half8v*)&lds[xbase + offB[s] + t * 2048];
#pragma unroll
      for (int mt = 0; mt < 2; ++mt) {
        f32x4 a = acc[t][mt];
        a = __builtin_amdgcn_mfma_f32_16x16x32_f16(wa[0][mt], xb[1], a, 0, 0, 0);
        a = __builtin_amdgcn_mfma_f32_16x16x32_f16(wa[1][mt], xb[0], a, 0, 0, 0);
        a = __builtin_amdgcn_mfma_f32_16x16x32_f16(wa[0][mt], xb[0], a, 0, 0, 0);
        acc[t][mt] = a;
      }
    }
    __builtin_amdgcn_s_setprio(0);
  };

  // prologue: issue X(0), W(0), X(1)  (order matters for vmcnt counting)
#pragma unroll
  for (int i = 0; i < 2; ++i)
    GLD16(gx[i], XB_(0) + i * 8192 + sb);
#pragma unroll
  for (int i = 0; i < 2; ++i) gx[i] += 32;
#pragma unroll
  for (int i = 0; i < 2; ++i)
    GLD16(gw[i], WB_(0) + i * 8192 + sb);
#pragma unroll
  for (int i = 0; i < 2; ++i) gw[i] += 32;
#pragma unroll
  for (int i = 0; i < 2; ++i)
    GLD16(gx[i], XB_(1) + i * 8192 + sb);
#pragma unroll
  for (int i = 0; i < 2; ++i) gx[i] += 32;

#pragma unroll
  for (int kk = 0; kk < 15; ++kk) {
    // issue W(kk+1) into the other W buffer
#pragma unroll
    for (int i = 0; i < 2; ++i)
      GLD16(gw[i], WB_(kk + 1) + i * 8192 + sb);
#pragma unroll
    for (int i = 0; i < 2; ++i) gw[i] += 32;
    if (kk < 14) {
      // issue X(kk+2) into the ring slot two ahead
#pragma unroll
      for (int i = 0; i < 2; ++i)
        GLD16(gx[i], XB_(kk + 2) + i * 8192 + sb);
#pragma unroll
      for (int i = 0; i < 2; ++i) gx[i] += 32;
    }
    __builtin_amdgcn_sched_barrier(0);
    // younger ops in flight: X(kk+1)=2, W(kk+1)=2, X(kk+2)=2 (when kk<14)
    if (kk < 14) asm volatile("s_waitcnt vmcnt(6)" ::: "memory");
    else         asm volatile("s_waitcnt vmcnt(4)" ::: "memory");
    __builtin_amdgcn_s_barrier();
    __builtin_amdgcn_sched_barrier(0);

    compute(WB_(kk), XB_(kk));

    asm volatile("s_waitcnt lgkmcnt(0)" ::: "memory"); // my ds_reads retired
    __builtin_amdgcn_sched_barrier(0);
    __builtin_amdgcn_s_barrier();                      // buffers free
  }
  // epilogue step 15: everything already issued, drain
  asm volatile("s_waitcnt vmcnt(0)" ::: "memory");
  __builtin_amdgcn_s_barrier();
  __builtin_amdgcn_sched_barrier(0);
  compute(WB_(15), XB_(15));

#undef WB_
#undef XB_

  // epilogue: unscale + bias + LIF over t
  const float* bias = (p == 0) ? bq : (p == 1) ? bk : bv;
  const int n = n0 + wn * 16 + ln15;
  if (p == 0) {
    unsigned char* spq = spikes_base;
#pragma unroll
    for (int mt = 0; mt < 2; ++mt) {
      int obase = o0 + wr * 32 + mt * 16 + lq * 4;
      float b4[4] = {bias[obase], bias[obase + 1], bias[obase + 2], bias[obase + 3]};
      float vm[4] = {0.f, 0.f, 0.f, 0.f};
#pragma unroll
      for (int t = 0; t < T_; ++t) {
        unsigned char sj[4];
#pragma unroll
        for (int r = 0; r < 4; ++r) {
          float y = acc[t][mt][r] * QKV_INV_SCALE + b4[r];
          float v = vm[r] + (y - vm[r]) * 0.5f;
          bool s = (v >= 1.0f);
          sj[r] = s ? 1 : 0;
          vm[r] = s ? 0.f : v;
        }
        *(uchar4*)&spq[((size_t)(t * B_ + b) * N_ + n) * C_ + obase] =
            make_uchar4(sj[0], sj[1], sj[2], sj[3]);
      }
    }
  } else {
    unsigned char* sp = spikes_base + (size_t)p * SPK_ELEMS;
#pragma unroll
    for (int mt = 0; mt < 2; ++mt)
#pragma unroll
      for (int r = 0; r < 4; ++r) {
        int o = o0 + wr * 32 + mt * 16 + lq * 4 + r;
        float bo = bias[o];
        float vmem = 0.f;
#pragma unroll
        for (int t = 0; t < T_; ++t) {
          float y = acc[t][mt][r] * QKV_INV_SCALE + bo;
          float v = vmem + (y - vmem) * 0.5f;
          bool s = (v >= 1.0f);
          sp[((size_t)(t * B_ + b) * C_ + o) * N_ + n] = s ? 1 : 0;
          vmem = s ? 0.f : v;
        }
      }
  }
}

// ---------------------------------------------------------------------------
// kv[t,b,h,d,e] = sum_n k[d,n]*v[e,n] via f16 MFMA (binary inputs, ints
// <=1024 in fp32 acc: bit-exact). grid (H,B,T), block 256 (wave = d-tile).
// ---------------------------------------------------------------------------
__global__ __launch_bounds__(256) void kv_f16(
    const unsigned char* __restrict__ sk, const unsigned char* __restrict__ sv,
    float* __restrict__ kvout)
{
  __shared__ _Float16 Kf[64 * 264];   // [d][n-chunk 256], pitch 264
  __shared__ _Float16 Vf[64 * 264];   // [e][n-chunk 256]
  const int tid = threadIdx.x;
  const int lane = tid & 63, wave = tid >> 6;
  const int ln15 = lane & 15, lq = lane >> 4;
  const int h = blockIdx.x, b = blockIdx.y, t = blockIdx.z;

  const unsigned char* kb = sk + ((size_t)(t * B_ + b) * C_ + h * D_) * N_;
  const unsigned char* vb = sv + ((size_t)(t * B_ + b) * C_ + h * D_) * N_;

  f32x4 acc[4];
#pragma unroll
  for (int et = 0; et < 4; ++et) acc[et] = (f32x4){0.f, 0.f, 0.f, 0.f};

  const int row = tid >> 2, seg = (tid & 3) * 64;   // 64B of one row per thread

  for (int nc = 0; nc < N_; nc += 256) {
    const unsigned char* kr = kb + (size_t)row * N_ + nc + seg;
    const unsigned char* vr = vb + (size_t)row * N_ + nc + seg;
#pragma unroll
    for (int j = 0; j < 16; ++j) {
      unsigned wk = *(const unsigned*)(kr + j * 4);
      unsigned lo = ((wk & 0xFFu) | ((wk & 0xFF00u) << 8)) * 0x3C00u;
      unsigned hi = (((wk >> 16) & 0xFFu) | ((wk >> 8) & 0xFF0000u)) * 0x3C00u;
      *(uint2*)&Kf[row * 264 + seg + j * 4] = make_uint2(lo, hi);
      unsigned wv = *(const unsigned*)(vr + j * 4);
      unsigned lo2 = ((wv & 0xFFu) | ((wv & 0xFF00u) << 8)) * 0x3C00u;
      unsigned hi2 = (((wv >> 16) & 0xFFu) | ((wv >> 8) & 0xFF0000u)) * 0x3C00u;
      *(uint2*)&Vf[row * 264 + seg + j * 4] = make_uint2(lo2, hi2);
    }
    __syncthreads();
#pragma unroll
    for (int ks = 0; ks < 8; ++ks) {
      half8v a = *(const half8v*)&Kf[(wave * 16 + ln15) * 264 + ks * 32 + lq * 8];
#pragma unroll
      for (int et = 0; et < 4; ++et) {
        half8v bf = *(const half8v*)&Vf[(et * 16 + ln15) * 264 + ks * 32 + lq * 8];
        acc[et] = __builtin_amdgcn_mfma_f32_16x16x32_f16(a, bf, acc[et], 0, 0, 0);
      }
    }
    __syncthreads();
  }

  float* o = kvout + ((size_t)(t * B_ + b) * H_ + h) * (D_ * D_);
#pragma unroll
  for (int et = 0; et < 4; ++et)
#pragma unroll
    for (int r = 0; r < 4; ++r) {
      int d = wave * 16 + lq * 4 + r;
      int e = et * 16 + ln15;
      o[d * D_ + e] = acc[et][r];
    }
}

// ---------------------------------------------------------------------------
// attn: out[e][n] = sum_d kvT[e][d] * q[n][d], *0.125, LIF over t.
// f16 MFMA exact. Writes sa f16 {0,1} at [t,b,n,c].
// grid (8 n-tiles of 128, H, B), block 256 (wave = e-tile).
// ---------------------------------------------------------------------------
__global__ __launch_bounds__(256) void attn_mfma(
    const unsigned char* __restrict__ sq2, const float* __restrict__ kv,
    unsigned short* __restrict__ sa)
{
  __shared__ _Float16 Qs[128 * 72];    // [n][d] pitch 72
  __shared__ _Float16 KVT[64 * 72];    // [e][d] pitch 72
  const int tid = threadIdx.x;
  const int lane = tid & 63, wave = tid >> 6;   // wave = e-tile
  const int ln15 = lane & 15, lq = lane >> 4;
  const int n0 = blockIdx.x * 128;
  const int h = blockIdx.y, b = blockIdx.z;

  f32x4 vm[8];
#pragma unroll
  for (int nt = 0; nt < 8; ++nt) vm[nt] = (f32x4){0.f, 0.f, 0.f, 0.f};

  for (int t = 0; t < T_; ++t) {
    __syncthreads();
    const float* kvb = kv + ((size_t)(t * B_ + b) * H_ + h) * (D_ * D_);
#pragma unroll
    for (int l = 0; l < 16; ++l) {
      int idx = l * 256 + tid;
      int e = idx & 63, d = idx >> 6;
      KVT[e * 72 + d] = (_Float16)kvb[d * 64 + e];   // ints <=1024: exact
    }
    const unsigned char* qb = sq2 + ((size_t)(t * B_ + b) * N_ + n0) * C_ + h * D_;
#pragma unroll
    for (int l = 0; l < 8; ++l) {
      int idx = l * 256 + tid;
      int n = idx >> 4, d4 = (idx & 15) * 4;
      uchar4 qu = *(const uchar4*)&qb[(size_t)n * C_ + d4];
      half4v hv;
      hv.x = qu.x ? (_Float16)1.0f : (_Float16)0.0f;
      hv.y = qu.y ? (_Float16)1.0f : (_Float16)0.0f;
      hv.z = qu.z ? (_Float16)1.0f : (_Float16)0.0f;
      hv.w = qu.w ? (_Float16)1.0f : (_Float16)0.0f;
      *(half4v*)&Qs[n * 72 + d4] = hv;
    }
    __syncthreads();

    half8v af[2];
#pragma unroll
    for (int kk = 0; kk < 2; ++kk)
      af[kk] = *(const half8v*)&KVT[(wave * 16 + ln15) * 72 + kk * 32 + lq * 8];

#pragma unroll
    for (int nt = 0; nt < 8; ++nt) {
      f32x4 a = (f32x4){0.f, 0.f, 0.f, 0.f};
#pragma unroll
      for (int kk = 0; kk < 2; ++kk) {
        half8v bf = *(const half8v*)&Qs[(nt * 16 + ln15) * 72 + kk * 32 + lq * 8];
        a = __builtin_amdgcn_mfma_f32_16x16x32_f16(af[kk], bf, a, 0, 0, 0);
      }
      unsigned short sj[4];
#pragma unroll
      for (int r = 0; r < 4; ++r) {
        float y = a[r] * 0.125f;
        float v = vm[nt][r] + (y - vm[nt][r]) * 0.5f;
        bool s = (v >= 1.0f);
        sj[r] = s ? 0x3C00 : 0;     // f16 one
        vm[nt][r] = s ? 0.f : v;
      }
      int n = n0 + nt * 16 + ln15;
      int c0 = h * D_ + wave * 16 + lq * 4;
      *(ushort4*)&sa[((size_t)(t * B_ + b) * N_ + n) * C_ + c0] =
          make_ushort4(sj[0], sj[1], sj[2], sj[3]);
    }
  }
}

// ---------------------------------------------------------------------------
// proj GEMM (2-product f16: W digits x exact f16 spikes) + connecting LIF.
// pv = acc * 2^-12 + bp. grid (4, 32, 16), block 256, R1 2-phase dbuf,
// vmcnt(6).  IN-KERNEL SWIZZLE: groups of 4 ot-sharers of one spike tile on
// one XCD, consecutive slots (2048 = 8 xcd x 64 chunks x 4 members).
// ---------------------------------------------------------------------------
__global__ __launch_bounds__(256) void proj_mfma(
    const _Float16* __restrict__ wb, const _Float16* __restrict__ sa,
    const float* __restrict__ bp, const float* __restrict__ x,
    float* __restrict__ out)
{
  // LDS: 2 buffers x { WS[2][128][32] f16 (16KB) + SS[4][32][32] f16 (8KB) }
  __shared__ __align__(16) char lds[49152];
  const int tid = threadIdx.x;
  const int lane = tid & 63, wave = tid >> 6;
  const int ln15 = lane & 15, lq = lane >> 4;

  const int l = blockIdx.x + 4 * blockIdx.y + 128 * blockIdx.z;
  const int xcd = l & 7, slot = l >> 3;
  const int g = (slot / 4) * 8 + xcd;       // 0..511 -> (ntb, b)
  const int ot = slot % 4;
  const int ntb = g & 31, b = g >> 5;
  const int o0 = ot * 128, n0 = ntb * 32;

  const _Float16* gsrc[6];
#pragma unroll
  for (int i = 0; i < 6; ++i) {
    int u = i * 256 + tid;
    if (u < 1024) {               // W region: 2 digits
      int s = u >> 9, rem = u & 511;
      int row = rem >> 2, pc = rem & 3;
      int lc = pc ^ ((row >> 1) & 3);
      gsrc[i] = wb + (((size_t)(3 * 2 + s)) << 18) + (size_t)(o0 + row) * C_ + lc * 8;
    } else {                      // spike region: 4t x 32 rows x 4 chunks
      int v = u - 1024;
      int t = v >> 7, rem2 = v & 127;
      int row = rem2 >> 2, pc = rem2 & 3;
      int lc = pc ^ ((row >> 1) & 3);
      gsrc[i] = sa + ((size_t)((t * B_ + b) * N_ + n0 + row)) * C_ + lc * 8;
    }
  }

  f32x4 acc[T_][2][2];
#pragma unroll
  for (int t = 0; t < T_; ++t)
#pragma unroll
    for (int mt = 0; mt < 2; ++mt)
#pragma unroll
      for (int nt = 0; nt < 2; ++nt)
        acc[t][mt][nt] = (f32x4){0.f, 0.f, 0.f, 0.f};

  int offA[2][2], offB[2];
#pragma unroll
  for (int s = 0; s < 2; ++s)
#pragma unroll
    for (int mt = 0; mt < 2; ++mt) {
      int r = wave * 32 + mt * 16 + ln15;
      offA[s][mt] = s * 8192 + r * 64 + ((lq ^ ((r >> 1) & 3)) << 4);
    }
#pragma unroll
  for (int nt = 0; nt < 2; ++nt) {
    int n = nt * 16 + ln15;
    offB[nt] = 16384 + n * 64 + ((lq ^ ((n >> 1) & 3)) << 4);
  }

  auto compute = [&](int cur) {
    half8v wa[2][2];
#pragma unroll
    for (int s = 0; s < 2; ++s)
#pragma unroll
      for (int mt = 0; mt < 2; ++mt)
        wa[s][mt] = *(const half8v*)&lds[cur + offA[s][mt]];

    __builtin_amdgcn_s_setprio(1);
#pragma unroll
    for (int t = 0; t < T_; ++t) {
      half8v xb[2];
#pragma unroll
      for (int nt = 0; nt < 2; ++nt)
        xb[nt] = *(const half8v*)&lds[cur + offB[nt] + t * 2048];
#pragma unroll
      for (int mt = 0; mt < 2; ++mt)
#pragma unroll
        for (int nt = 0; nt < 2; ++nt) {
          f32x4 a = acc[t][mt][nt];
          a = __builtin_amdgcn_mfma_f32_16x16x32_f16(wa[1][mt], xb[nt], a, 0, 0, 0);
          a = __builtin_amdgcn_mfma_f32_16x16x32_f16(wa[0][mt], xb[nt], a, 0, 0, 0);
          acc[t][mt][nt] = a;
        }
    }
    __builtin_amdgcn_s_setprio(0);
  };

  // prologue: stage tile 0 into buffer 0
#pragma unroll
  for (int i = 0; i < 6; ++i)
    GLD16(gsrc[i], i * 4096 + (tid & 192) * 16);
#pragma unroll
  for (int i = 0; i < 6; ++i) gsrc[i] += 32;

  for (int kk = 0; kk < 15; ++kk) {
    const int cur = (kk & 1) * 24576;
    const int nxt = 24576 - cur;
#pragma unroll
    for (int i = 0; i < 6; ++i)
      GLD16(gsrc[i], nxt + i * 4096 + (tid & 192) * 16);
#pragma unroll
    for (int i = 0; i < 6; ++i) gsrc[i] += 32;
    __builtin_amdgcn_sched_barrier(0);
    asm volatile("s_waitcnt vmcnt(6)" ::: "memory");   // current tile landed
    __builtin_amdgcn_s_barrier();
    __builtin_amdgcn_sched_barrier(0);

    compute(cur);

    asm volatile("s_waitcnt lgkmcnt(0)" ::: "memory");
    __builtin_amdgcn_sched_barrier(0);
    __builtin_amdgcn_s_barrier();
  }
  asm volatile("s_waitcnt vmcnt(0)" ::: "memory");
  __builtin_amdgcn_s_barrier();
  __builtin_amdgcn_sched_barrier(0);
  compute(24576);

  // epilogue: connecting LIF with identity shortcut
#pragma unroll
  for (int mt = 0; mt < 2; ++mt)
#pragma unroll
    for (int r = 0; r < 4; ++r) {
      int o = o0 + wave * 32 + mt * 16 + lq * 4 + r;
      float bo = bp[o];
#pragma unroll
      for (int nt = 0; nt < 2; ++nt) {
        int n = n0 + nt * 16 + ln15;
        float vmem = 0.f;
#pragma unroll
        for (int t = 0; t < T_; ++t) {
          size_t base = ((size_t)(t * B_ + b) * C_ + o) * N_ + n;
          float xv = x[base];
          float pv = acc[t][mt][nt][r] * PROJ_INV_SCALE + bo;
          float v = vmem + ((pv + xv) - vmem) * 0.5f;
          bool s = (v >= 1.0f);
          out[base] = s ? 1.0f : 0.0f;
          vmem = s ? 0.f : v;
        }
      }
    }
}

// ---------------------------------------------------------------------------
extern "C" void kernel_launch(void* const* d_in, const int* in_sizes, int n_in,
                              void* d_out, int out_size, void* d_ws, size_t ws_size,
                              hipStream_t stream)
{
  const float* x  = (const float*)d_in[0];
  const float* Wq = (const float*)d_in[1];
  const float* bq = (const float*)d_in[2];
  const float* Wk = (const float*)d_in[3];
  const float* bk = (const float*)d_in[4];
  const float* Wv = (const float*)d_in[5];
  const float* bv = (const float*)d_in[6];
  const float* Wp = (const float*)d_in[7];
  const float* bp = (const float*)d_in[8];
  (void)in_sizes; (void)n_in; (void)out_size; (void)ws_size;

  unsigned char* ws = (unsigned char*)d_ws;
  unsigned char* sq = ws;                       // [t,b,n,c] transposed
  unsigned char* sk = ws + SPK_ELEMS;
  unsigned char* sv = ws + 2 * SPK_ELEMS;
  float* kvbuf = (float*)(ws + KV_OFF_N);
  _Float16* wb = (_Float16*)(ws + WB_OFF_N);
  _Float16* xs = (_Float16*)(ws + XS_OFF_N);
  unsigned short* sa = (unsigned short*)xs;  // alias digit-0 (xs dead before attn)
  float* out = (float*)d_out;

  convert_w<<<4096, 256, 0, stream>>>(Wq, Wk, Wv, Wp, wb);
  convert_x<<<dim3(32, 16, 64), dim3(32, 8), 0, stream>>>(x, xs);
  qkv_mfma<<<dim3(12, 32, 16), 512, 0, stream>>>(wb, xs, bq, bk, bv, ws);
  kv_f16<<<dim3(8, 16, 4), 256, 0, stream>>>(sk, sv, kvbuf);
  attn_mfma<<<dim3(8, 8, 16), 256, 0, stream>>>(sq, kvbuf, sa);
  proj_mfma<<<dim3(4, 32, 16), 256, 0, stream>>>(wb, (const _Float16*)sa, bp, x, out);
}

// Round 9
// 748.207 us; speedup vs baseline: 1.0131x; 1.0131x over previous
//
#include <hip/hip_runtime.h>

// Problem constants
#define T_ 4
#define B_ 16
#define C_ 512
#define N_ 1024
#define H_ 8
#define D_ 64
#define SPK_ELEMS (33554432ull)   // T*B*C*N

typedef _Float16 half8v __attribute__((ext_vector_type(8)));
typedef _Float16 half4v __attribute__((ext_vector_type(4)));
typedef float f32x4 __attribute__((ext_vector_type(4)));

// ---------------- workspace layout (bytes) ----------------
// sq:  [0, 33554432)            uint8 q spikes  [t,b,n,c]  (TRANSPOSED)
// sk:  [33554432, 67108864)     uint8 k spikes  [t,b,c,n]
// sv:  [67108864, 100663296)    uint8 v spikes  [t,b,c,n]
// kv:  [100663296, 109051904)   fp32  [t,b,h,d,e]
// wb:  [109051904, 113246208)   f16   [p=4][digit=2][512][512], W pre-scaled by 2^12
// xs:  [113246208, 247463936)   f16   [digit=2][t][b][n][c],    x pre-scaled by 2^11
// sa:  aliases xs digit-0 region (xs dead before attn writes it); f16 {0,1}
#define KV_OFF_N  100663296ull
#define WB_OFF_N  109051904ull
#define XS_OFF_N  113246208ull

#define QKV_INV_SCALE (1.0f / 8388608.0f)   // 2^-23  (Sx=2^11 * Sw=2^12)
#define PROJ_INV_SCALE (1.0f / 4096.0f)     // 2^-12  (Sw only; spikes unscaled)

#define GLD16(gp, loff) \
  __builtin_amdgcn_global_load_lds( \
      (const __attribute__((address_space(1))) void*)(gp), \
      (__attribute__((address_space(3))) void*)(lds + (loff)), 16, 0, 0)

// ---------------------------------------------------------------------------
// W [4 mats][512][512] fp32 -> wb [p][2][512][512] f16 digits of W*2^12.
// ---------------------------------------------------------------------------
__global__ __launch_bounds__(256) void convert_w(
    const float* __restrict__ w0, const float* __restrict__ w1,
    const float* __restrict__ w2, const float* __restrict__ w3,
    _Float16* __restrict__ wb)
{
  int idx = blockIdx.x * 256 + threadIdx.x;      // 0..1048575
  int p = idx >> 18, rem = idx & 262143;
  const float* src = (p == 0) ? w0 : (p == 1) ? w1 : (p == 2) ? w2 : w3;
  float v = src[rem] * 4096.0f;                  // exact pow2 scale
  _Float16 h1 = (_Float16)v;
  float r1 = v - (float)h1;
  _Float16 h2 = (_Float16)r1;
  size_t base = ((size_t)(p * 2)) << 18;
  wb[base + rem] = h1;
  wb[base + 262144 + rem] = h2;
}

// ---------------------------------------------------------------------------
// x [t,b,c,n] fp32 -> xs [digit=2][t,b,n,c] f16 digits of x*2^11 (transposed)
// ---------------------------------------------------------------------------
__global__ __launch_bounds__(256) void convert_x(
    const float* __restrict__ x, _Float16* __restrict__ xs)
{
  __shared__ float tile[32][33];
  const int tb = blockIdx.z;
  const int c0 = blockIdx.y * 32, n0 = blockIdx.x * 32;
  const int tx = threadIdx.x, ty = threadIdx.y;
  const float* src = x + ((size_t)tb * C_ + c0) * N_ + n0;
#pragma unroll
  for (int k = 0; k < 4; ++k)
    tile[ty + 8 * k][tx] = src[(size_t)(ty + 8 * k) * N_ + tx];
  __syncthreads();
#pragma unroll
  for (int k = 0; k < 4; ++k) {
    int r = ty + 8 * k;                       // n-offset within tile
    float v = tile[tx][r] * 2048.0f;          // exact pow2 scale
    _Float16 h1 = (_Float16)v;
    float r1 = v - (float)h1;
    _Float16 h2 = (_Float16)r1;
    size_t o = ((size_t)tb * N_ + n0 + r) * C_ + c0 + tx;
    xs[o] = h1;
    xs[o + 33554432ull] = h2;
  }
}

// ---------------------------------------------------------------------------
// Fused q/k/v GEMM (3-product f16 2x2-digit MFMA, fp32 acc) + LIF.
// Block tile 128o x 32n x 4t.  grid (12, 32, 16) + XCD-group swizzle (R5).
// 512-thread blocks (R7): 8 waves = 4 o-quarters x 2 n-halves.
//
// R8 SINGLE-BARRIER K-loop: per step {stage W(t+1), X(t+2) -> compute(t) ->
// vmcnt(2) -> s_barrier}.  Correctness: a wave's ds_reads of step t retire
// before its last MFMA (compiler lgkm waits), hence before its barrier
// arrival -> the one barrier certifies reads-done for the slots stage(t+1)
// overwrites (W slot (t+2)&1, X slot (t+3)%3).  vmcnt(2) before the barrier
// = this wave's W(t+1)+X(t+1) landed; barrier makes it global.  Halves
// barrier count (32->16) and removes the 16 lgkmcnt(0) drains.
// ---------------------------------------------------------------------------
__global__ __launch_bounds__(512) void qkv_mfma(
    const _Float16* __restrict__ wb, const _Float16* __restrict__ xs,
    const float* __restrict__ bq, const float* __restrict__ bk,
    const float* __restrict__ bv, unsigned char* __restrict__ spikes_base)
{
  // LDS: W dbuf 2x16KB at [0,32768); X tribuf 3x16KB at [32768,81920)
  __shared__ __align__(16) char lds[81920];
  const int tid = threadIdx.x;
  const int lane = tid & 63, wave = tid >> 6;   // 0..7
  const int ln15 = lane & 15, lq = lane >> 4;
  const int wr = wave & 3, wn = wave >> 2;      // o-quarter, n-half

  // XCD-group swizzle (bijective: 6144 = 8 xcd x 64 chunks x 12 members)
  const int l = blockIdx.x + 12 * blockIdx.y + 384 * blockIdx.z;
  const int xcd = l & 7, slot = l >> 3;
  const int g = (slot / 12) * 8 + xcd;      // 0..511 -> (ntb, b)
  const int m = slot % 12;                  // 0..11  -> (ot | p)
  const int ot = m & 3, p = m >> 2;
  const int ntb = g & 31, b = g >> 5;
  const int o0 = ot * 128, n0 = ntb * 32;

#define WB_(k) (((k) & 1) * 16384)
#define XB_(k) (32768 + ((k) % 3) * 16384)

  // W staging sources: 2 x 16B per thread per k-step (16KB/step, 512 thr)
  const _Float16* gw[2];
#pragma unroll
  for (int i = 0; i < 2; ++i) {
    int u = i * 512 + tid;        // 0..1023: [dig s][row 128][chunk 4]
    int s = u >> 9, rem = u & 511;
    int row = rem >> 2, pc = rem & 3;
    int lc = pc ^ ((row >> 1) & 3);
    gw[i] = wb + (((size_t)(p * 2 + s)) << 18) + (size_t)(o0 + row) * C_ + lc * 8;
  }
  // X staging sources: 2 x 16B per thread per k-step (16KB/step)
  const _Float16* gx[2];
#pragma unroll
  for (int i = 0; i < 2; ++i) {
    int v = i * 512 + tid;        // 0..1023: [dig s][t 4][row 32][chunk 4]
    int s = v >> 9, rem = v & 511;
    int t = rem >> 7, rem2 = rem & 127;
    int row = rem2 >> 2, pc = rem2 & 3;
    int lc = pc ^ ((row >> 1) & 3);
    gx[i] = xs + ((size_t)s * 33554432ull) +
            ((size_t)((t * B_ + b) * N_ + n0 + row)) * C_ + lc * 8;
  }
  // LDS staging dest (wave-uniform base; lane*16 added by HW)
  const int sb = (tid & 448) * 16;   // wave * 1024

  f32x4 acc[T_][2];   // [t][mt]; wave's 32o x 16n slice
#pragma unroll
  for (int t = 0; t < T_; ++t)
#pragma unroll
    for (int mt = 0; mt < 2; ++mt)
      acc[t][mt] = (f32x4){0.f, 0.f, 0.f, 0.f};

  int offA[2][2], offB[2];
#pragma unroll
  for (int s = 0; s < 2; ++s) {
#pragma unroll
    for (int mt = 0; mt < 2; ++mt) {
      int r = wr * 32 + mt * 16 + ln15;
      offA[s][mt] = s * 8192 + r * 64 + ((lq ^ ((r >> 1) & 3)) << 4);
    }
    {
      int n = wn * 16 + ln15;
      offB[s] = s * 8192 + n * 64 + ((lq ^ ((n >> 1) & 3)) << 4);
    }
  }

  auto compute = [&](int wbase, int xbase) {
    half8v wa[2][2];
#pragma unroll
    for (int s = 0; s < 2; ++s)
#pragma unroll
      for (int mt = 0; mt < 2; ++mt)
        wa[s][mt] = *(const half8v*)&lds[wbase + offA[s][mt]];

    __builtin_amdgcn_s_setprio(1);
#pragma unroll
    for (int t = 0; t < T_; ++t) {
      half8v xb[2];
#pragma unroll
      for (int s = 0; s < 2; ++s)
        xb[s] = *(const half8v*)&lds[xbase + offB[s] + t * 2048];
#pragma unroll
      for (int mt = 0; mt < 2; ++mt) {
        f32x4 a = acc[t][mt];
        a = __builtin_amdgcn_mfma_f32_16x16x32_f16(wa[0][mt], xb[1], a, 0, 0, 0);
        a = __builtin_amdgcn_mfma_f32_16x16x32_f16(wa[1][mt], xb[0], a, 0, 0, 0);
        a = __builtin_amdgcn_mfma_f32_16x16x32_f16(wa[0][mt], xb[0], a, 0, 0, 0);
        acc[t][mt] = a;
      }
    }
    __builtin_amdgcn_s_setprio(0);
  };

  // prologue: issue X(0), W(0), X(1); wait own X(0)+W(0); barrier
#pragma unroll
  for (int i = 0; i < 2; ++i)
    GLD16(gx[i], XB_(0) + i * 8192 + sb);
#pragma unroll
  for (int i = 0; i < 2; ++i) gx[i] += 32;
#pragma unroll
  for (int i = 0; i < 2; ++i)
    GLD16(gw[i], WB_(0) + i * 8192 + sb);
#pragma unroll
  for (int i = 0; i < 2; ++i) gw[i] += 32;
#pragma unroll
  for (int i = 0; i < 2; ++i)
    GLD16(gx[i], XB_(1) + i * 8192 + sb);
#pragma unroll
  for (int i = 0; i < 2; ++i) gx[i] += 32;
  asm volatile("s_waitcnt vmcnt(2)" ::: "memory");   // X(0), W(0) landed
  __builtin_amdgcn_s_barrier();
  __builtin_amdgcn_sched_barrier(0);

#pragma unroll
  for (int kk = 0; kk < 16; ++kk) {
    // stage W(kk+1) into the other W buffer
    if (kk < 15) {
#pragma unroll
      for (int i = 0; i < 2; ++i)
        GLD16(gw[i], WB_(kk + 1) + i * 8192 + sb);
#pragma unroll
      for (int i = 0; i < 2; ++i) gw[i] += 32;
    }
    // stage X(kk+2) into the ring slot two ahead
    if (kk < 14) {
#pragma unroll
      for (int i = 0; i < 2; ++i)
        GLD16(gx[i], XB_(kk + 2) + i * 8192 + sb);
#pragma unroll
      for (int i = 0; i < 2; ++i) gx[i] += 32;
    }
    __builtin_amdgcn_sched_barrier(0);

    compute(WB_(kk), XB_(kk));

    if (kk < 15) {
      __builtin_amdgcn_sched_barrier(0);
      // wait own W(kk+1)+X(kk+1) landed; X(kk+2)'s 2 ops stay in flight
      if (kk < 14) asm volatile("s_waitcnt vmcnt(2)" ::: "memory");
      else         asm volatile("s_waitcnt vmcnt(0)" ::: "memory");
      __builtin_amdgcn_s_barrier();   // global: slot kk reads done, kk+1 ready
      __builtin_amdgcn_sched_barrier(0);
    }
  }

#undef WB_
#undef XB_

  // epilogue: unscale + bias + LIF over t
  const float* bias = (p == 0) ? bq : (p == 1) ? bk : bv;
  const int n = n0 + wn * 16 + ln15;
  if (p == 0) {
    unsigned char* spq = spikes_base;
#pragma unroll
    for (int mt = 0; mt < 2; ++mt) {
      int obase = o0 + wr * 32 + mt * 16 + lq * 4;
      float b4[4] = {bias[obase], bias[obase + 1], bias[obase + 2], bias[obase + 3]};
      float vm[4] = {0.f, 0.f, 0.f, 0.f};
#pragma unroll
      for (int t = 0; t < T_; ++t) {
        unsigned char sj[4];
#pragma unroll
        for (int r = 0; r < 4; ++r) {
          float y = acc[t][mt][r] * QKV_INV_SCALE + b4[r];
          float v = vm[r] + (y - vm[r]) * 0.5f;
          bool s = (v >= 1.0f);
          sj[r] = s ? 1 : 0;
          vm[r] = s ? 0.f : v;
        }
        *(uchar4*)&spq[((size_t)(t * B_ + b) * N_ + n) * C_ + obase] =
            make_uchar4(sj[0], sj[1], sj[2], sj[3]);
      }
    }
  } else {
    unsigned char* sp = spikes_base + (size_t)p * SPK_ELEMS;
#pragma unroll
    for (int mt = 0; mt < 2; ++mt)
#pragma unroll
      for (int r = 0; r < 4; ++r) {
        int o = o0 + wr * 32 + mt * 16 + lq * 4 + r;
        float bo = bias[o];
        float vmem = 0.f;
#pragma unroll
        for (int t = 0; t < T_; ++t) {
          float y = acc[t][mt][r] * QKV_INV_SCALE + bo;
          float v = vmem + (y - vmem) * 0.5f;
          bool s = (v >= 1.0f);
          sp[((size_t)(t * B_ + b) * C_ + o) * N_ + n] = s ? 1 : 0;
          vmem = s ? 0.f : v;
        }
      }
  }
}

// ---------------------------------------------------------------------------
// kv[t,b,h,d,e] = sum_n k[d,n]*v[e,n] via f16 MFMA (binary inputs, ints
// <=1024 in fp32 acc: bit-exact). grid (H,B,T), block 256 (wave = d-tile).
// ---------------------------------------------------------------------------
__global__ __launch_bounds__(256) void kv_f16(
    const unsigned char* __restrict__ sk, const unsigned char* __restrict__ sv,
    float* __restrict__ kvout)
{
  __shared__ _Float16 Kf[64 * 264];   // [d][n-chunk 256], pitch 264
  __shared__ _Float16 Vf[64 * 264];   // [e][n-chunk 256]
  const int tid = threadIdx.x;
  const int lane = tid & 63, wave = tid >> 6;
  const int ln15 = lane & 15, lq = lane >> 4;
  const int h = blockIdx.x, b = blockIdx.y, t = blockIdx.z;

  const unsigned char* kb = sk + ((size_t)(t * B_ + b) * C_ + h * D_) * N_;
  const unsigned char* vb = sv + ((size_t)(t * B_ + b) * C_ + h * D_) * N_;

  f32x4 acc[4];
#pragma unroll
  for (int et = 0; et < 4; ++et) acc[et] = (f32x4){0.f, 0.f, 0.f, 0.f};

  const int row = tid >> 2, seg = (tid & 3) * 64;   // 64B of one row per thread

  for (int nc = 0; nc < N_; nc += 256) {
    const unsigned char* kr = kb + (size_t)row * N_ + nc + seg;
    const unsigned char* vr = vb + (size_t)row * N_ + nc + seg;
#pragma unroll
    for (int j = 0; j < 16; ++j) {
      unsigned wk = *(const unsigned*)(kr + j * 4);
      unsigned lo = ((wk & 0xFFu) | ((wk & 0xFF00u) << 8)) * 0x3C00u;
      unsigned hi = (((wk >> 16) & 0xFFu) | ((wk >> 8) & 0xFF0000u)) * 0x3C00u;
      *(uint2*)&Kf[row * 264 + seg + j * 4] = make_uint2(lo, hi);
      unsigned wv = *(const unsigned*)(vr + j * 4);
      unsigned lo2 = ((wv & 0xFFu) | ((wv & 0xFF00u) << 8)) * 0x3C00u;
      unsigned hi2 = (((wv >> 16) & 0xFFu) | ((wv >> 8) & 0xFF0000u)) * 0x3C00u;
      *(uint2*)&Vf[row * 264 + seg + j * 4] = make_uint2(lo2, hi2);
    }
    __syncthreads();
#pragma unroll
    for (int ks = 0; ks < 8; ++ks) {
      half8v a = *(const half8v*)&Kf[(wave * 16 + ln15) * 264 + ks * 32 + lq * 8];
#pragma unroll
      for (int et = 0; et < 4; ++et) {
        half8v bf = *(const half8v*)&Vf[(et * 16 + ln15) * 264 + ks * 32 + lq * 8];
        acc[et] = __builtin_amdgcn_mfma_f32_16x16x32_f16(a, bf, acc[et], 0, 0, 0);
      }
    }
    __syncthreads();
  }

  float* o = kvout + ((size_t)(t * B_ + b) * H_ + h) * (D_ * D_);
#pragma unroll
  for (int et = 0; et < 4; ++et)
#pragma unroll
    for (int r = 0; r < 4; ++r) {
      int d = wave * 16 + lq * 4 + r;
      int e = et * 16 + ln15;
      o[d * D_ + e] = acc[et][r];
    }
}

// ---------------------------------------------------------------------------
// attn: out[e][n] = sum_d kvT[e][d] * q[n][d], *0.125, LIF over t.
// f16 MFMA exact. Writes sa f16 {0,1} at [t,b,n,c].
// grid (8 n-tiles of 128, H, B), block 256 (wave = e-tile).
// ---------------------------------------------------------------------------
__global__ __launch_bounds__(256) void attn_mfma(
    const unsigned char* __restrict__ sq2, const float* __restrict__ kv,
    unsigned short* __restrict__ sa)
{
  __shared__ _Float16 Qs[128 * 72];    // [n][d] pitch 72
  __shared__ _Float16 KVT[64 * 72];    // [e][d] pitch 72
  const int tid = threadIdx.x;
  const int lane = tid & 63, wave = tid >> 6;   // wave = e-tile
  const int ln15 = lane & 15, lq = lane >> 4;
  const int n0 = blockIdx.x * 128;
  const int h = blockIdx.y, b = blockIdx.z;

  f32x4 vm[8];
#pragma unroll
  for (int nt = 0; nt < 8; ++nt) vm[nt] = (f32x4){0.f, 0.f, 0.f, 0.f};

  for (int t = 0; t < T_; ++t) {
    __syncthreads();
    const float* kvb = kv + ((size_t)(t * B_ + b) * H_ + h) * (D_ * D_);
#pragma unroll
    for (int l = 0; l < 16; ++l) {
      int idx = l * 256 + tid;
      int e = idx & 63, d = idx >> 6;
      KVT[e * 72 + d] = (_Float16)kvb[d * 64 + e];   // ints <=1024: exact
    }
    const unsigned char* qb = sq2 + ((size_t)(t * B_ + b) * N_ + n0) * C_ + h * D_;
#pragma unroll
    for (int l = 0; l < 8; ++l) {
      int idx = l * 256 + tid;
      int n = idx >> 4, d4 = (idx & 15) * 4;
      uchar4 qu = *(const uchar4*)&qb[(size_t)n * C_ + d4];
      half4v hv;
      hv.x = qu.x ? (_Float16)1.0f : (_Float16)0.0f;
      hv.y = qu.y ? (_Float16)1.0f : (_Float16)0.0f;
      hv.z = qu.z ? (_Float16)1.0f : (_Float16)0.0f;
      hv.w = qu.w ? (_Float16)1.0f : (_Float16)0.0f;
      *(half4v*)&Qs[n * 72 + d4] = hv;
    }
    __syncthreads();

    half8v af[2];
#pragma unroll
    for (int kk = 0; kk < 2; ++kk)
      af[kk] = *(const half8v*)&KVT[(wave * 16 + ln15) * 72 + kk * 32 + lq * 8];

#pragma unroll
    for (int nt = 0; nt < 8; ++nt) {
      f32x4 a = (f32x4){0.f, 0.f, 0.f, 0.f};
#pragma unroll
      for (int kk = 0; kk < 2; ++kk) {
        half8v bf = *(const half8v*)&Qs[(nt * 16 + ln15) * 72 + kk * 32 + lq * 8];
        a = __builtin_amdgcn_mfma_f32_16x16x32_f16(af[kk], bf, a, 0, 0, 0);
      }
      unsigned short sj[4];
#pragma unroll
      for (int r = 0; r < 4; ++r) {
        float y = a[r] * 0.125f;
        float v = vm[nt][r] + (y - vm[nt][r]) * 0.5f;
        bool s = (v >= 1.0f);
        sj[r] = s ? 0x3C00 : 0;     // f16 one
        vm[nt][r] = s ? 0.f : v;
      }
      int n = n0 + nt * 16 + ln15;
      int c0 = h * D_ + wave * 16 + lq * 4;
      *(ushort4*)&sa[((size_t)(t * B_ + b) * N_ + n) * C_ + c0] =
          make_ushort4(sj[0], sj[1], sj[2], sj[3]);
    }
  }
}

// ---------------------------------------------------------------------------
// proj GEMM (2-product f16: W digits x exact f16 spikes) + connecting LIF.
// pv = acc * 2^-12 + bp. grid (4, 32, 16), block 256, R1 2-phase dbuf,
// vmcnt(6).  IN-KERNEL SWIZZLE: groups of 4 ot-sharers of one spike tile on
// one XCD, consecutive slots (2048 = 8 xcd x 64 chunks x 4 members).
// ---------------------------------------------------------------------------
__global__ __launch_bounds__(256) void proj_mfma(
    const _Float16* __restrict__ wb, const _Float16* __restrict__ sa,
    const float* __restrict__ bp, const float* __restrict__ x,
    float* __restrict__ out)
{
  // LDS: 2 buffers x { WS[2][128][32] f16 (16KB) + SS[4][32][32] f16 (8KB) }
  __shared__ __align__(16) char lds[49152];
  const int tid = threadIdx.x;
  const int lane = tid & 63, wave = tid >> 6;
  const int ln15 = lane & 15, lq = lane >> 4;

  const int l = blockIdx.x + 4 * blockIdx.y + 128 * blockIdx.z;
  const int xcd = l & 7, slot = l >> 3;
  const int g = (slot / 4) * 8 + xcd;       // 0..511 -> (ntb, b)
  const int ot = slot % 4;
  const int ntb = g & 31, b = g >> 5;
  const int o0 = ot * 128, n0 = ntb * 32;

  const _Float16* gsrc[6];
#pragma unroll
  for (int i = 0; i < 6; ++i) {
    int u = i * 256 + tid;
    if (u < 1024) {               // W region: 2 digits
      int s = u >> 9, rem = u & 511;
      int row = rem >> 2, pc = rem & 3;
      int lc = pc ^ ((row >> 1) & 3);
      gsrc[i] = wb + (((size_t)(3 * 2 + s)) << 18) + (size_t)(o0 + row) * C_ + lc * 8;
    } else {                      // spike region: 4t x 32 rows x 4 chunks
      int v = u - 1024;
      int t = v >> 7, rem2 = v & 127;
      int row = rem2 >> 2, pc = rem2 & 3;
      int lc = pc ^ ((row >> 1) & 3);
      gsrc[i] = sa + ((size_t)((t * B_ + b) * N_ + n0 + row)) * C_ + lc * 8;
    }
  }

  f32x4 acc[T_][2][2];
#pragma unroll
  for (int t = 0; t < T_; ++t)
#pragma unroll
    for (int mt = 0; mt < 2; ++mt)
#pragma unroll
      for (int nt = 0; nt < 2; ++nt)
        acc[t][mt][nt] = (f32x4){0.f, 0.f, 0.f, 0.f};

  int offA[2][2], offB[2];
#pragma unroll
  for (int s = 0; s < 2; ++s)
#pragma unroll
    for (int mt = 0; mt < 2; ++mt) {
      int r = wave * 32 + mt * 16 + ln15;
      offA[s][mt] = s * 8192 + r * 64 + ((lq ^ ((r >> 1) & 3)) << 4);
    }
#pragma unroll
  for (int nt = 0; nt < 2; ++nt) {
    int n = nt * 16 + ln15;
    offB[nt] = 16384 + n * 64 + ((lq ^ ((n >> 1) & 3)) << 4);
  }

  auto compute = [&](int cur) {
    half8v wa[2][2];
#pragma unroll
    for (int s = 0; s < 2; ++s)
#pragma unroll
      for (int mt = 0; mt < 2; ++mt)
        wa[s][mt] = *(const half8v*)&lds[cur + offA[s][mt]];

    __builtin_amdgcn_s_setprio(1);
#pragma unroll
    for (int t = 0; t < T_; ++t) {
      half8v xb[2];
#pragma unroll
      for (int nt = 0; nt < 2; ++nt)
        xb[nt] = *(const half8v*)&lds[cur + offB[nt] + t * 2048];
#pragma unroll
      for (int mt = 0; mt < 2; ++mt)
#pragma unroll
        for (int nt = 0; nt < 2; ++nt) {
          f32x4 a = acc[t][mt][nt];
          a = __builtin_amdgcn_mfma_f32_16x16x32_f16(wa[1][mt], xb[nt], a, 0, 0, 0);
          a = __builtin_amdgcn_mfma_f32_16x16x32_f16(wa[0][mt], xb[nt], a, 0, 0, 0);
          acc[t][mt][nt] = a;
        }
    }
    __builtin_amdgcn_s_setprio(0);
  };

  // prologue: stage tile 0 into buffer 0
#pragma unroll
  for (int i = 0; i < 6; ++i)
    GLD16(gsrc[i], i * 4096 + (tid & 192) * 16);
#pragma unroll
  for (int i = 0; i < 6; ++i) gsrc[i] += 32;

  for (int kk = 0; kk < 15; ++kk) {
    const int cur = (kk & 1) * 24576;
    const int nxt = 24576 - cur;
#pragma unroll
    for (int i = 0; i < 6; ++i)
      GLD16(gsrc[i], nxt + i * 4096 + (tid & 192) * 16);
#pragma unroll
    for (int i = 0; i < 6; ++i) gsrc[i] += 32;
    __builtin_amdgcn_sched_barrier(0);
    asm volatile("s_waitcnt vmcnt(6)" ::: "memory");   // current tile landed
    __builtin_amdgcn_s_barrier();
    __builtin_amdgcn_sched_barrier(0);

    compute(cur);

    asm volatile("s_waitcnt lgkmcnt(0)" ::: "memory");
    __builtin_amdgcn_sched_barrier(0);
    __builtin_amdgcn_s_barrier();
  }
  asm volatile("s_waitcnt vmcnt(0)" ::: "memory");
  __builtin_amdgcn_s_barrier();
  __builtin_amdgcn_sched_barrier(0);
  compute(24576);

  // epilogue: connecting LIF with identity shortcut
#pragma unroll
  for (int mt = 0; mt < 2; ++mt)
#pragma unroll
    for (int r = 0; r < 4; ++r) {
      int o = o0 + wave * 32 + mt * 16 + lq * 4 + r;
      float bo = bp[o];
#pragma unroll
      for (int nt = 0; nt < 2; ++nt) {
        int n = n0 + nt * 16 + ln15;
        float vmem = 0.f;
#pragma unroll
        for (int t = 0; t < T_; ++t) {
          size_t base = ((size_t)(t * B_ + b) * C_ + o) * N_ + n;
          float xv = x[base];
          float pv = acc[t][mt][nt][r] * PROJ_INV_SCALE + bo;
          float v = vmem + ((pv + xv) - vmem) * 0.5f;
          bool s = (v >= 1.0f);
          out[base] = s ? 1.0f : 0.0f;
          vmem = s ? 0.f : v;
        }
      }
    }
}

// ---------------------------------------------------------------------------
extern "C" void kernel_launch(void* const* d_in, const int* in_sizes, int n_in,
                              void* d_out, int out_size, void* d_ws, size_t ws_size,
                              hipStream_t stream)
{
  const float* x  = (const float*)d_in[0];
  const float* Wq = (const float*)d_in[1];
  const float* bq = (const float*)d_in[2];
  const float* Wk = (const float*)d_in[3];
  const float* bk = (const float*)d_in[4];
  const float* Wv = (const float*)d_in[5];
  const float* bv = (const float*)d_in[6];
  const float* Wp = (const float*)d_in[7];
  const float* bp = (const float*)d_in[8];
  (void)in_sizes; (void)n_in; (void)out_size; (void)ws_size;

  unsigned char* ws = (unsigned char*)d_ws;
  unsigned char* sq = ws;                       // [t,b,n,c] transposed
  unsigned char* sk = ws + SPK_ELEMS;
  unsigned char* sv = ws + 2 * SPK_ELEMS;
  float* kvbuf = (float*)(ws + KV_OFF_N);
  _Float16* wb = (_Float16*)(ws + WB_OFF_N);
  _Float16* xs = (_Float16*)(ws + XS_OFF_N);
  unsigned short* sa = (unsigned short*)xs;  // alias digit-0 (xs dead before attn)
  float* out = (float*)d_out;

  convert_w<<<4096, 256, 0, stream>>>(Wq, Wk, Wv, Wp, wb);
  convert_x<<<dim3(32, 16, 64), dim3(32, 8), 0, stream>>>(x, xs);
  qkv_mfma<<<dim3(12, 32, 16), 512, 0, stream>>>(wb, xs, bq, bk, bv, ws);
  kv_f16<<<dim3(8, 16, 4), 256, 0, stream>>>(sk, sv, kvbuf);
  attn_mfma<<<dim3(8, 8, 16), 256, 0, stream>>>(sq, kvbuf, sa);
  proj_mfma<<<dim3(4, 32, 16), 256, 0, stream>>>(wb, (const _Float16*)sa, bp, x, out);
}